// Round 9
// baseline (637.732 us; speedup 1.0000x reference)
//
#include <hip/hip_runtime.h>
#include <stdint.h>

#define BB 256      // batch
#define TT 200      // timesteps
#define INN 1568    // inputs
#define OO 100      // outputs
#define PAIRS 784   // INN/2
#define NHALF 12800 // (BB*OO)/2

typedef unsigned long long u64;
typedef __attribute__((ext_vector_type(4))) int v4i;  // clang-native for NT loads

// ---------------- threefry2x32 (JAX-compatible) ----------------
__device__ __forceinline__ void tf_round(uint32_t& x0, uint32_t& x1, int r) {
    x0 += x1;
    x1 = (x1 << r) | (x1 >> (32 - r));
    x1 ^= x0;
}

__device__ __forceinline__ void threefry(uint32_t k0, uint32_t k1,
                                         uint32_t x0, uint32_t x1,
                                         uint32_t& o0, uint32_t& o1) {
    uint32_t k2 = k0 ^ k1 ^ 0x1BD11BDAu;
    x0 += k0; x1 += k1;
    tf_round(x0,x1,13); tf_round(x0,x1,15); tf_round(x0,x1,26); tf_round(x0,x1,6);
    x0 += k1; x1 += k2 + 1u;
    tf_round(x0,x1,17); tf_round(x0,x1,29); tf_round(x0,x1,16); tf_round(x0,x1,24);
    x0 += k2; x1 += k0 + 2u;
    tf_round(x0,x1,13); tf_round(x0,x1,15); tf_round(x0,x1,26); tf_round(x0,x1,6);
    x0 += k0; x1 += k1 + 3u;
    tf_round(x0,x1,17); tf_round(x0,x1,29); tf_round(x0,x1,16); tf_round(x0,x1,24);
    x0 += k1; x1 += k2 + 4u;
    tf_round(x0,x1,13); tf_round(x0,x1,15); tf_round(x0,x1,26); tf_round(x0,x1,6);
    o0 = x0 + k2; o1 = x1 + k0 + 5u;
}

// K1: fused winners + x->bit pack, 64-thread blocks.
// winners [blocks 0,800): exp(logits)==0 so categorical == gumbel argmax;
// g=-log(-log(u)) strictly increasing in u, u in (bits>>9) -> integer argmax.
// pack [blocks 800+): 32 B per thread (8 bit-columns) so each wave issue is
// 2 KB contiguous (vs 1 KB in r8) — fewer partial DRAM pages, half the
// concurrent streams.
__global__ __launch_bounds__(64) void k_winbit(const int* __restrict__ x,
                                               uint8_t* __restrict__ widx,
                                               u64* __restrict__ bitB) {
    if (blockIdx.x < 800) {
        int idx = blockIdx.x * 64 + threadIdx.x;   // < TT*BB = 51200
        int t = idx >> 8, b = idx & 255;
        uint32_t fk0, fk1;
        threefry(0u, 42u, 0u, (uint32_t)t, fk0, fk1);   // fold_in(key(42), t)
        uint32_t bestkey = 0u;
        int bo = 0;
        int nbase = b * OO;
        for (int o = 0; o < OO; ++o) {
            uint32_t n = (uint32_t)(nbase + o);
            uint32_t lo = (n < NHALF) ? n : n - NHALF;
            uint32_t v0, v1;
            threefry(fk0, fk1, lo, lo + NHALF, v0, v1);
            uint32_t bits = (n < NHALF) ? v0 : v1;
            uint32_t key = bits >> 9;       // monotone proxy for gumbel
            if (key > bestkey) { bestkey = key; bo = o; }
        }
        widx[idx] = (uint8_t)bo;
    } else {
        int idx = (blockIdx.x - 800) * 64 + threadIdx.x; // < 4*TT*196 = 156800
        int wb = idx / (TT * 196);
        int r = idx - wb * (TT * 196);
        int t = r / 196;
        int ig2 = r - t * 196;                // group of 8 inputs (2 v4i)
        const v4i* xp = (const v4i*)x;
        u64 m0=0,m1=0,m2=0,m3=0,m4=0,m5=0,m6=0,m7=0;
        for (int j = 0; j < 64; ++j) {
            int b = wb * 64 + j;
            size_t base = ((size_t)b * TT + t) * 392 + ig2 * 2;
            v4i va = __builtin_nontemporal_load(&xp[base]);
            v4i vb = __builtin_nontemporal_load(&xp[base + 1]);
            u64 bit = 1ull << j;
            if (va.x) m0 |= bit;
            if (va.y) m1 |= bit;
            if (va.z) m2 |= bit;
            if (va.w) m3 |= bit;
            if (vb.x) m4 |= bit;
            if (vb.y) m5 |= bit;
            if (vb.z) m6 |= bit;
            if (vb.w) m7 |= bit;
        }
        u64* dst = bitB + ((size_t)(t * 4 + wb)) * INN + 8 * ig2;
        dst[0] = m0; dst[1] = m1; dst[2] = m2; dst[3] = m3;
        dst[4] = m4; dst[5] = m5; dst[6] = m6; dst[7] = m7;
    }
}

// K2: fused firstwin + winpost. One block per o; widx staged in LDS once
// (65-word padded rows -> conflict-free for both access phases). [proven r5]
__global__ __launch_bounds__(256) void k_fwpost(const uint8_t* __restrict__ widx,
                                                u64* __restrict__ winbits,
                                                u64* __restrict__ postbits,
                                                uint32_t* __restrict__ cnt) {
    __shared__ uint32_t wl32[TT * 65];   // wl32[t*65 + q] = widx[t*256 + q*4 ..+3]
    __shared__ int fwl[BB];
    int o = blockIdx.x;
    int tid = threadIdx.x;
    const uint32_t* wsrc = (const uint32_t*)widx;
    for (int g = tid; g < TT * 64; g += 256) {
        int t = g >> 6, w = g & 63;
        wl32[t * 65 + w] = wsrc[g];
    }
    __syncthreads();
    if (tid < 64) {
        int f0 = 255, f1 = 255, f2 = 255, f3 = 255;
        for (int t = 0; t < TT; ++t) {
            uint32_t w4 = wl32[t * 65 + tid];
            if (((w4      ) & 255u) == (uint32_t)o && f0 == 255) f0 = t;
            if (((w4 >>  8) & 255u) == (uint32_t)o && f1 == 255) f1 = t;
            if (((w4 >> 16) & 255u) == (uint32_t)o && f2 == 255) f2 = t;
            if (((w4 >> 24) & 255u) == (uint32_t)o && f3 == 255) f3 = t;
        }
        fwl[4 * tid + 0] = f0; fwl[4 * tid + 1] = f1;
        fwl[4 * tid + 2] = f2; fwl[4 * tid + 3] = f3;
    }
    __syncthreads();
    if (tid < TT) {
        int t = tid;
        u64 wbA[4], pbA[4];
        uint32_t c = 0;
        #pragma unroll
        for (int k = 0; k < 4; ++k) {
            u64 wacc = 0, pacc = 0;
            for (int q2 = 0; q2 < 16; ++q2) {
                uint32_t w4 = wl32[t * 65 + k * 16 + q2];
                #pragma unroll
                for (int j = 0; j < 4; ++j) {
                    int bl = q2 * 4 + j;
                    bool win = (((w4 >> (8 * j)) & 255u) == (uint32_t)o);
                    c += win ? 1u : 0u;
                    bool post = (fwl[k * 64 + q2 * 4 + j] < t) && !win;
                    u64 bit = 1ull << bl;
                    if (win)  wacc |= bit;
                    if (post) pacc |= bit;
                }
            }
            wbA[k] = wacc; pbA[k] = pacc;
        }
        size_t base = (size_t)(t * OO + o) * 4;
        #pragma unroll
        for (int k = 0; k < 4; ++k) {
            winbits[base + k] = wbA[k];
            postbits[base + k] = pbA[k];
        }
        cnt[t * OO + o] = c;
    }
}

// K3: popc with inline sliding window, 64-thread blocks, u8x4 packing.
//   pot = OR_{s=0..9} bitB[t-s], ltp = pot | bitB[t-10]
//   packed[(tl*OO+o)*PAIRS + p] = lt0 | pp0<<8 | lt1<<16 | pp1<<24 (saturate 255)
__global__ __launch_bounds__(64) void k_popcW(
        const u64* __restrict__ bitB,
        const u64* __restrict__ winbits,
        const u64* __restrict__ postbits,
        uint32_t* __restrict__ packed,
        int t0) {
    __shared__ u64 winS[OO * 4];
    __shared__ u64 postS[OO * 4];
    int tl = blockIdx.y;
    int t = t0 + tl;
    int tid = threadIdx.x;
    for (int idx = tid; idx < OO * 4; idx += 64) {
        winS[idx]  = winbits[(size_t)t * OO * 4 + idx];
        postS[idx] = postbits[(size_t)t * OO * 4 + idx];
    }
    __syncthreads();
    int p = blockIdx.x * 64 + tid;
    if (p >= PAIRS) return;
    int i0 = p, i1 = p + PAIRS;
    u64 p0=0,p1=0,p2=0,p3=0,p4=0,p5=0,p6=0,p7=0;
    int ttlo = (t - 9 < 0) ? 0 : t - 9;
    for (int tt = ttlo; tt <= t; ++tt) {
        const u64* row = bitB + (size_t)tt * 4 * INN;
        p0 |= row[i0];           p1 |= row[INN + i0];
        p2 |= row[2 * INN + i0]; p3 |= row[3 * INN + i0];
        p4 |= row[i1];           p5 |= row[INN + i1];
        p6 |= row[2 * INN + i1]; p7 |= row[3 * INN + i1];
    }
    u64 l0=p0,l1=p1,l2=p2,l3=p3,l4=p4,l5=p5,l6=p6,l7=p7;
    if (t >= 10) {
        const u64* row = bitB + (size_t)(t - 10) * 4 * INN;
        l0 |= row[i0];           l1 |= row[INN + i0];
        l2 |= row[2 * INN + i0]; l3 |= row[3 * INN + i0];
        l4 |= row[i1];           l5 |= row[INN + i1];
        l6 |= row[2 * INN + i1]; l7 |= row[3 * INN + i1];
    }
    uint32_t* orow = packed + (size_t)tl * OO * PAIRS + p;
    #pragma unroll 4
    for (int o = 0; o < OO; ++o) {
        const u64* w = &winS[o * 4];
        const u64* s = &postS[o * 4];
        uint32_t lt0 = __popcll(l0 & w[0]) + __popcll(l1 & w[1])
                     + __popcll(l2 & w[2]) + __popcll(l3 & w[3]);
        uint32_t lt1 = __popcll(l4 & w[0]) + __popcll(l5 & w[1])
                     + __popcll(l6 & w[2]) + __popcll(l7 & w[3]);
        uint32_t pp0 = __popcll(p0 & s[0]) + __popcll(p1 & s[1])
                     + __popcll(p2 & s[2]) + __popcll(p3 & s[3]);
        uint32_t pp1 = __popcll(p4 & s[0]) + __popcll(p5 & s[1])
                     + __popcll(p6 & s[2]) + __popcll(p7 & s[3]);
        lt0 = (lt0 > 255u) ? 255u : lt0;  pp0 = (pp0 > 255u) ? 255u : pp0;
        lt1 = (lt1 > 255u) ? 255u : lt1;  pp1 = (pp1 > 255u) ? 255u : pp1;
        uint32_t v = lt0 | (pp0 << 8) | (lt1 << 16) | (pp1 << 24);
        __builtin_nontemporal_store(v, &orow[(size_t)o * PAIRS]);
    }
}

// K4: chains (y<100) + prior (y==100), 64-thread blocks.
// 16-deep prefetch ring: 16 iters x ~70 cyc = 1120 cyc in-flight window
// covers the ~900-cyc HBM latency of the nontemporal packed stream.
__global__ __launch_bounds__(64) void k_chainsPrior(
        const float* __restrict__ L0,
        const float* __restrict__ p0arr,
        const uint32_t* __restrict__ packed,
        const uint32_t* __restrict__ cnt,
        float* __restrict__ outL,
        float* __restrict__ outp,
        int t0, int ct, int first, int do_prior) {
    if (blockIdx.y == OO) {
        if (!do_prior || blockIdx.x != 0) return;
        int l = threadIdx.x;
        bool has2 = (l + 64) < OO;
        float pa = p0arr[l];
        float pb = has2 ? p0arr[l + 64] : -1e30f;
        auto normalize = [&]() {
            pa = fminf(fmaxf(pa, -5.0f), 0.0f);
            if (has2) pb = fminf(fmaxf(pb, -5.0f), 0.0f);
            float mx = has2 ? fmaxf(pa, pb) : pa;
            #pragma unroll
            for (int s = 32; s > 0; s >>= 1) mx = fmaxf(mx, __shfl_xor(mx, s, 64));
            float sm = expf(pa - mx) + (has2 ? expf(pb - mx) : 0.0f);
            #pragma unroll
            for (int s = 32; s > 0; s >>= 1) sm += __shfl_xor(sm, s, 64);
            float lse = logf(sm) + mx;
            pa -= lse;
            if (has2) pb -= lse;
        };
        normalize();
        for (int t = 0; t < TT; ++t) {
            float eta = 0.001f / (float)(t + 1);
            float wma = (float)cnt[t * OO + l] * (1.0f / 256.0f);
            pa += eta * ((-5.0f * pa - 1.0f) * wma - (1.0f - wma));
            if (has2) {
                float wmb = (float)cnt[t * OO + l + 64] * (1.0f / 256.0f);
                pb += eta * ((-5.0f * pb - 1.0f) * wmb - (1.0f - wmb));
            }
            normalize();
        }
        outp[l] = pa;
        if (has2) outp[l + 64] = pb;
        return;
    }
    // ---- weight chains ----
    int o = blockIdx.y;
    int p = blockIdx.x * 64 + threadIdx.x;
    if (p >= PAIRS) return;
    int i0 = p, i1 = p + PAIRS;
    float a, b2;
    if (first) {
        a  = L0[(size_t)i0 * OO + o];
        b2 = L0[(size_t)i1 * OO + o];
        a  = fminf(fmaxf(a,  -5.0f), 0.0f);
        b2 = fminf(fmaxf(b2, -5.0f), 0.0f);
        float m = fmaxf(a, b2), mn = fminf(a, b2);
        float lse = __logf(1.0f + __expf(mn - m)) + m;
        a -= lse; b2 -= lse;
    } else {
        a  = outL[(size_t)i0 * OO + o];
        b2 = outL[(size_t)i1 * OO + o];
    }
    const uint32_t* src = packed + (size_t)o * PAIRS + p;
    const size_t tstride = (size_t)OO * PAIRS;
    uint32_t c[16];
    #pragma unroll
    for (int k = 0; k < 16; ++k) {
        int idx = (k < ct) ? k : (ct - 1);
        c[k] = __builtin_nontemporal_load(&src[(size_t)idx * tstride]);
    }
    #pragma unroll 16
    for (int tl = 0; tl < ct; ++tl) {
        uint32_t cur = c[tl & 15];
        int nx = tl + 16; if (nx >= ct) nx = ct - 1;
        c[tl & 15] = __builtin_nontemporal_load(&src[(size_t)nx * tstride]);
        int t = t0 + tl;
        float cwin = (float)cnt[t * OO + o];
        float lt0 = (float)(cur & 255u),         pp0 = (float)((cur >> 8) & 255u);
        float lt1 = (float)((cur >> 16) & 255u), pp1 = (float)(cur >> 24);
        float eta = 0.001f / (float)(t + 1);
        float dw0 = (5.0f * __expf(-a)  - 1.0f) * (lt0 * (1.0f/256.0f))
                  + (cwin - lt0 - pp0) * (1.0f/256.0f);
        float dw1 = (5.0f * __expf(-b2) - 1.0f) * (lt1 * (1.0f/256.0f))
                  + (cwin - lt1 - pp1) * (1.0f/256.0f);
        a  += eta * dw0;
        b2 += eta * dw1;
        a  = fminf(fmaxf(a,  -5.0f), 0.0f);
        b2 = fminf(fmaxf(b2, -5.0f), 0.0f);
        float m = fmaxf(a, b2), mn = fminf(a, b2);
        float lse = __logf(1.0f + __expf(mn - m)) + m;
        a -= lse; b2 -= lse;
    }
    outL[(size_t)i0 * OO + o] = a;
    outL[(size_t)i1 * OO + o] = b2;
}

extern "C" void kernel_launch(void* const* d_in, const int* in_sizes, int n_in,
                              void* d_out, int out_size, void* d_ws, size_t ws_size,
                              hipStream_t stream) {
    const int*   x  = (const int*)d_in[0];
    const float* L0 = (const float*)d_in[1];
    const float* p0 = (const float*)d_in[2];
    float* out = (float*)d_out;

    char* ws = (char*)d_ws;
    size_t off = 0;
    auto alloc = [&](size_t bytes) -> void* {
        off = (off + 255) & ~(size_t)255;
        void* p = ws + off;
        off += bytes;
        return p;
    };
    uint8_t*  widx     = (uint8_t*) alloc((size_t)TT * BB);
    uint32_t* cnt      = (uint32_t*)alloc((size_t)TT * OO * 4);
    u64*      winbits  = (u64*)     alloc((size_t)TT * OO * 4 * 8);
    u64*      postbits = (u64*)     alloc((size_t)TT * OO * 4 * 8);
    u64*      bitB     = (u64*)     alloc((size_t)TT * 4 * INN * 8);
    // base ≈ 11.5 MB

    // largest t-chunk whose packed (4 B/pair) fits in the remaining workspace
    static const int cands[] = {200, 100, 50, 25, 20, 10, 8, 5, 4, 2, 1};
    int CT = 1;
    size_t base_off = (off + 255) & ~(size_t)255;
    for (int c = 0; c < 11; ++c) {
        size_t need = base_off + (size_t)cands[c] * OO * PAIRS * 4;
        if (need <= ws_size) { CT = cands[c]; break; }
    }
    uint32_t* packed = (uint32_t*)(ws + base_off);

    hipLaunchKernelGGL(k_winbit, dim3(800 + 2450), dim3(64), 0, stream, x, widx, bitB);
    hipLaunchKernelGGL(k_fwpost, dim3(OO), dim3(256), 0, stream,
                       widx, winbits, postbits, cnt);
    for (int t0 = 0; t0 < TT; t0 += CT) {
        int ct = (t0 + CT <= TT) ? CT : (TT - t0);
        int last = (t0 + ct >= TT) ? 1 : 0;
        hipLaunchKernelGGL(k_popcW, dim3((PAIRS + 63) / 64, ct), dim3(64), 0, stream,
                           bitB, winbits, postbits, packed, t0);
        hipLaunchKernelGGL(k_chainsPrior, dim3((PAIRS + 63) / 64, OO + 1), dim3(64),
                           0, stream, L0, p0, packed, cnt, out,
                           out + (size_t)INN * OO, t0, ct, (t0 == 0) ? 1 : 0, last);
    }
}